// Round 4
// baseline (21904.417 us; speedup 1.0000x reference)
//
#include <hip/hip_runtime.h>

#define BB 256
#define LL 128
#define HH 512
#define H4 2048

typedef unsigned short us;
typedef __attribute__((ext_vector_type(8))) __bf16 bf16x8;
typedef __attribute__((ext_vector_type(4))) float f32x4;

__device__ __forceinline__ float bf2f(us s) {
    unsigned u = ((unsigned)s) << 16;
    return __builtin_bit_cast(float, u);
}
__device__ __forceinline__ us f2bf(float f) {
    unsigned u = __builtin_bit_cast(unsigned, f);
    return (us)((u + 0x7fffu + ((u >> 16) & 1u)) >> 16);
}
__device__ __forceinline__ float sigm(float x) { return 1.f / (1.f + __expf(-x)); }
__device__ __forceinline__ float tanh_(float x) { return 1.f - 2.f / (1.f + __expf(2.f * x)); }
__device__ __forceinline__ bf16x8 ldb8(const us* p) { return *(const bf16x8*)(const void*)p; }

// ---- grid barrier: 256 co-resident blocks, sense-reversing, agent scope ----
__device__ __forceinline__ void gridbar(unsigned* bar, unsigned* gen) {
    __syncthreads();
    if (threadIdx.x == 0) {
        __threadfence();  // release: wbl2 so other XCDs see our writes via L3
        unsigned g = __hip_atomic_load(gen, __ATOMIC_RELAXED, __HIP_MEMORY_SCOPE_AGENT);
        unsigned a = __hip_atomic_fetch_add(bar, 1u, __ATOMIC_ACQ_REL, __HIP_MEMORY_SCOPE_AGENT);
        if (a == 255u) {
            __hip_atomic_store(bar, 0u, __ATOMIC_RELAXED, __HIP_MEMORY_SCOPE_AGENT);
            __hip_atomic_store(gen, g + 1u, __ATOMIC_RELEASE, __HIP_MEMORY_SCOPE_AGENT);
        } else {
            while (__hip_atomic_load(gen, __ATOMIC_RELAXED, __HIP_MEMORY_SCOPE_AGENT) == g)
                __builtin_amdgcn_s_sleep(1);
        }
        __threadfence();  // acquire: inv L1/L2 so we don't read stale lines
    }
    __syncthreads();
}

// ---- one 16x64 output tile of D[M,512] = A[M,512] @ Bt[512,512]^T (bf16 in, bf16 out) ----
__device__ __forceinline__ void gemm16x64(const us* __restrict__ A, const us* __restrict__ Bt,
                                          us* __restrict__ D, int m0, int n0, int lane) {
    int l15 = lane & 15, quad = lane >> 4;
    f32x4 acc[4] = {};
    const us* Ar = A + (size_t)(m0 + l15) * HH + quad * 8;
    const us* Br = Bt + (size_t)(n0 + l15) * HH + quad * 8;
#pragma unroll 4
    for (int kk = 0; kk < 16; ++kk) {
        bf16x8 a = ldb8(Ar + kk * 32);
#pragma unroll
        for (int tt = 0; tt < 4; ++tt) {
            bf16x8 b = ldb8(Br + (size_t)tt * 16 * HH + kk * 32);
            acc[tt] = __builtin_amdgcn_mfma_f32_16x16x32_bf16(a, b, acc[tt], 0, 0, 0);
        }
    }
#pragma unroll
    for (int tt = 0; tt < 4; ++tt)
#pragma unroll
        for (int r = 0; r < 4; ++r)
            D[(size_t)(m0 + quad * 4 + r) * HH + n0 + tt * 16 + l15] = f2bf(acc[tt][r]);
}

// ================= the whole model: one persistent kernel =================
// grid 256 x 256 threads (4 waves/block, 1 block/CU). Waves 0-1 of each block own
// MFMA tasks (512 = 16 batch-tiles x 32 colgroups); LSTM c-state stays in registers
// from encoder through decoder (same wave owns the same (b0,c0) in both).
__global__ __launch_bounds__(256, 1) void k_all(
    const int* __restrict__ xs, const int* __restrict__ argsort,
    const float* __restrict__ enc_Wi, const float* __restrict__ enc_Wh, const float* __restrict__ enc_b,
    const float* __restrict__ dec_Wi, const float* __restrict__ dec_Wh, const float* __restrict__ dec_b,
    const float* __restrict__ w1, const float* __restrict__ w2, const float* __restrict__ vt,
    float* __restrict__ out, char* __restrict__ ws) {
    unsigned* bar = (unsigned*)ws;
    unsigned* gen = bar + 1;
    float* din = (float*)(ws + 256);            // 2*256*4 = 2048 (zeroed by memset)
    us* hdec = (us*)(ws + 2304);                // 2*256*512*2
    us* q = (us*)(ws + 526592);                 // 256*512*2
    us* ctx = (us*)(ws + 788736);               // 256*512*2
    us* wiR = (us*)(ws + 1050880);              // 2048*512*2
    us* whE = (us*)(ws + 3148032);              // 2048*512*2
    us* whD = (us*)(ws + 5245184);              // 2048*512*2
    us* w1B = (us*)(ws + 7342336);              // 512*512*2
    us* w2B = (us*)(ws + 7866624);              // 512*512*2
    us* enc_out = (us*)(ws + 8390912);          // 256*128*512*2
    us* enc_w1 = (us*)(ws + 41945344);          // 256*128*512*2 -> end 75499776

    __shared__ float scs[LL];
    __shared__ float aj[LL];
    __shared__ float redm[2];
    __shared__ float reds[2];

    const int tid = threadIdx.x, blk = blockIdx.x;
    const int w = tid >> 6, lane = tid & 63;
    const int l15 = lane & 15, quad = lane >> 4;
    const int gw = blk * 4 + w;       // 0..1023
    const int t2 = blk * 2 + w;       // wave-task id for w<2: 0..511
    const bool encw = (w < 2);

    // ---- phase 0: weight conversion f32 -> bf16 ws copies ----
    for (int i = blk * 256 + tid; i < H4 * HH; i += 65536) {
        whE[i] = f2bf(enc_Wh[i]);
        whD[i] = f2bf(dec_Wh[i]);
        int r = i >> 9, c = i & 511;
        wiR[i] = f2bf(dec_Wi[(size_t)r * 513 + c]);
    }
    for (int i = blk * 256 + tid; i < HH * HH; i += 65536) {
        w1B[i] = f2bf(w1[i]);
        w2B[i] = f2bf(w2[i]);
    }
    gridbar(bar, gen);

    // ---- per-task constants (hoisted out of the time loops) ----
    int b0 = 0, c0 = 0, col = 0;
    float biE[4], wiE[4], biD[4], wlD[4];
    if (encw) {
        b0 = (t2 & 15) * 16;
        c0 = (t2 >> 4) * 16;
        col = c0 + l15;
#pragma unroll
        for (int g = 0; g < 4; ++g) {
            int rg = g * HH + col;
            biE[g] = enc_b[rg];
            wiE[g] = enc_Wi[rg];
            biD[g] = dec_b[rg];
            wlD[g] = dec_Wi[(size_t)rg * 513 + 512];
        }
    }
    float creg[4] = {0.f, 0.f, 0.f, 0.f};  // LSTM c, lives in regs encoder->decoder

    // ---- phase 1: encoder, 128 steps, 1 barrier each ----
    for (int t = 0; t < LL; ++t) {
        if (encw) {
            f32x4 acc[4] = {};
            if (t > 0) {
                const us* Arow = enc_out + ((size_t)(b0 + l15) * LL + (t - 1)) * HH + quad * 8;
                const us* Brow = whE + (size_t)col * HH + quad * 8 - (size_t)l15 * HH + (size_t)l15 * HH;
                Brow = whE + (size_t)(c0 + l15) * HH + quad * 8;
#pragma unroll 4
                for (int kk = 0; kk < 16; ++kk) {
                    bf16x8 a = ldb8(Arow + kk * 32);
#pragma unroll
                    for (int g = 0; g < 4; ++g) {
                        bf16x8 b = ldb8(Brow + (size_t)g * HH * HH + kk * 32);
                        acc[g] = __builtin_amdgcn_mfma_f32_16x16x32_bf16(a, b, acc[g], 0, 0, 0);
                    }
                }
            }
#pragma unroll
            for (int r = 0; r < 4; ++r) {
                int b = b0 + quad * 4 + r;
                float xv = (float)xs[b * LL + t];
                float zi = acc[0][r] + biE[0] + xv * wiE[0];
                float zf = acc[1][r] + biE[1] + xv * wiE[1];
                float zg = acc[2][r] + biE[2] + xv * wiE[2];
                float zo = acc[3][r] + biE[3] + xv * wiE[3];
                float c_ = sigm(zf) * creg[r] + sigm(zi) * tanh_(zg);
                creg[r] = c_;
                us hb = f2bf(sigm(zo) * tanh_(c_));
                enc_out[((size_t)b * LL + t) * HH + col] = hb;
                if (t == LL - 1) hdec[(size_t)b * HH + col] = hb;
            }
        }
        gridbar(bar, gen);
    }

    // ---- phase 2: enc_w1 = enc_out @ w1^T (16384 wave-tasks over 1024 waves) ----
    for (int task = gw; task < 16384; task += 1024) {
        int m0 = (task >> 3) * 16, n0 = (task & 7) * 64;
        gemm16x64(enc_out, w1B, enc_w1, m0, n0, lane);
    }
    gridbar(bar, gen);

    // ---- phase 3: decoder, 128 steps, 3 barriers each ----
    const int k0 = lane * 8;
    float vtk[8];
#pragma unroll
    for (int j = 0; j < 8; ++j) vtk[j] = vt[k0 + j];

    for (int t = 0; t < LL; ++t) {
        us* hcur = hdec + (size_t)(t & 1) * BB * HH;
        us* hnxt = hdec + (size_t)((t + 1) & 1) * BB * HH;
        float* dcur = din + (t & 1) * BB;
        float* dnxt = din + ((t + 1) & 1) * BB;

        // q = hcur @ w2^T : 128 wave-tasks spread over even blocks' wave 0
        if (w == 0 && (blk & 1) == 0) {
            int qt = blk >> 1;
            gemm16x64(hcur, w2B, q, (qt >> 3) * 16, (qt & 7) * 64, lane);
        }
        gridbar(bar, gen);

        // attention: block handles batch b = blk (256 threads)
        {
            bf16x8 qv = ldb8(q + (size_t)blk * HH + k0);
            float qk[8];
#pragma unroll
            for (int j = 0; j < 8; ++j) qk[j] = (float)qv[j];
            const us* wbase = enc_w1 + (size_t)blk * LL * HH + k0;
#pragma unroll 4
            for (int i = 0; i < 32; ++i) {
                int l = i * 4 + w;
                bf16x8 e8 = ldb8(wbase + (size_t)l * HH);
                float s = 0.f;
#pragma unroll
                for (int j = 0; j < 8; ++j) s += tanh_((float)e8[j] + qk[j]) * vtk[j];
#pragma unroll
                for (int off = 1; off < 64; off <<= 1) s += __shfl_xor(s, off);
                if (lane == 0) scs[l] = s;
            }
            __syncthreads();
            bool act = tid < 128;
            float sc = act ? scs[tid] : -1e30f;
            float m = sc;
#pragma unroll
            for (int off = 1; off < 64; off <<= 1) m = fmaxf(m, __shfl_xor(m, off));
            if (act && lane == 0) redm[w] = m;
            __syncthreads();
            float M = fmaxf(redm[0], redm[1]);
            float e = act ? __expf(sc - M) : 0.f;
            float ss = e;
#pragma unroll
            for (int off = 1; off < 64; off <<= 1) ss += __shfl_xor(ss, off);
            if (act && lane == 0) reds[w] = ss;
            __syncthreads();
            float S = reds[0] + reds[1];
            if (act) {
                out[((size_t)blk * LL + t) * LL + tid] = sc - M - __logf(S);
                aj[tid] = e / S;
            }
            __syncthreads();
            const us* ep = enc_out + (size_t)blk * LL * HH + tid;
            float cx0 = 0.f, cx1 = 0.f;
#pragma unroll 8
            for (int l2 = 0; l2 < LL; ++l2) {
                cx0 += aj[l2] * bf2f(ep[(size_t)l2 * HH]);
                cx1 += aj[l2] * bf2f(ep[(size_t)l2 * HH + 256]);
            }
            ctx[(size_t)blk * HH + tid] = f2bf(cx0);
            ctx[(size_t)blk * HH + tid + 256] = f2bf(cx1);
            if (tid == 0) {
                int idx = argsort[blk * LL + t];
                dnxt[blk] = (float)xs[blk * LL + idx];
            }
        }
        gridbar(bar, gen);

        // decoder LSTM: z = [ctx,din]@Wi^T + h@Wh^T + b (same task map as encoder)
        if (encw) {
            f32x4 acc[4] = {};
            const us* A1 = ctx + (size_t)(b0 + l15) * HH + quad * 8;
            const us* B1 = wiR + (size_t)(c0 + l15) * HH + quad * 8;
#pragma unroll 4
            for (int kk = 0; kk < 16; ++kk) {
                bf16x8 a = ldb8(A1 + kk * 32);
#pragma unroll
                for (int g = 0; g < 4; ++g) {
                    bf16x8 b = ldb8(B1 + (size_t)g * HH * HH + kk * 32);
                    acc[g] = __builtin_amdgcn_mfma_f32_16x16x32_bf16(a, b, acc[g], 0, 0, 0);
                }
            }
            const us* A2 = hcur + (size_t)(b0 + l15) * HH + quad * 8;
            const us* B2 = whD + (size_t)(c0 + l15) * HH + quad * 8;
#pragma unroll 4
            for (int kk = 0; kk < 16; ++kk) {
                bf16x8 a = ldb8(A2 + kk * 32);
#pragma unroll
                for (int g = 0; g < 4; ++g) {
                    bf16x8 b = ldb8(B2 + (size_t)g * HH * HH + kk * 32);
                    acc[g] = __builtin_amdgcn_mfma_f32_16x16x32_bf16(a, b, acc[g], 0, 0, 0);
                }
            }
#pragma unroll
            for (int r = 0; r < 4; ++r) {
                int b = b0 + quad * 4 + r;
                float dv = dcur[b];
                float zi = acc[0][r] + biD[0] + dv * wlD[0];
                float zf = acc[1][r] + biD[1] + dv * wlD[1];
                float zg = acc[2][r] + biD[2] + dv * wlD[2];
                float zo = acc[3][r] + biD[3] + dv * wlD[3];
                float c_ = sigm(zf) * creg[r] + sigm(zi) * tanh_(zg);
                creg[r] = c_;
                hnxt[(size_t)b * HH + col] = f2bf(sigm(zo) * tanh_(c_));
            }
        }
        gridbar(bar, gen);
    }
}

extern "C" void kernel_launch(void* const* d_in, const int* in_sizes, int n_in,
                              void* d_out, int out_size, void* d_ws, size_t ws_size,
                              hipStream_t stream) {
    const int* xs = (const int*)d_in[0];
    const int* argsort = (const int*)d_in[2];
    const float* enc_Wi = (const float*)d_in[3];
    const float* enc_Wh = (const float*)d_in[4];
    const float* enc_b = (const float*)d_in[5];
    const float* dec_Wi = (const float*)d_in[6];
    const float* dec_Wh = (const float*)d_in[7];
    const float* dec_b = (const float*)d_in[8];
    const float* w1 = (const float*)d_in[9];
    const float* w2 = (const float*)d_in[10];
    const float* vt = (const float*)d_in[11];
    float* out = (float*)d_out;
    char* ws = (char*)d_ws;

    // zero barrier state + din double-buffer
    hipMemsetAsync(ws, 0, 2304, stream);
    k_all<<<256, 256, 0, stream>>>(xs, argsort, enc_Wi, enc_Wh, enc_b,
                                   dec_Wi, dec_Wh, dec_b, w1, w2, vt, out, ws);
    (void)in_sizes; (void)n_in; (void)out_size; (void)ws_size;
}

// Round 5
// 14265.236 us; speedup vs baseline: 1.5355x; 1.5355x over previous
//
#include <hip/hip_runtime.h>

#define BB 256
#define LL 128
#define HH 512
#define H4 2048

typedef unsigned short us;
typedef __attribute__((ext_vector_type(8))) __bf16 bf16x8;
typedef __attribute__((ext_vector_type(4))) float f32x4;

__device__ __forceinline__ float bf2f(us s) {
    unsigned u = ((unsigned)s) << 16;
    return __builtin_bit_cast(float, u);
}
__device__ __forceinline__ us f2bf(float f) {
    unsigned u = __builtin_bit_cast(unsigned, f);
    return (us)((u + 0x7fffu + ((u >> 16) & 1u)) >> 16);
}
__device__ __forceinline__ float sigm(float x) { return 1.f / (1.f + __expf(-x)); }
__device__ __forceinline__ float tanh_(float x) { return 1.f - 2.f / (1.f + __expf(2.f * x)); }
__device__ __forceinline__ bf16x8 ldb8(const us* p) { return *(const bf16x8*)(const void*)p; }

// ---- grid barrier v2: per-block arrive slots (128B apart) + block-0 parallel gather ----
// Epoch-based: no flag resets. Arrives are 256 INDEPENDENT release stores (parallel at the
// coherence point) instead of round 4's 256 serialized fetch_adds on one line (~43us/barrier).
__device__ __forceinline__ void gridbar(unsigned* arr, unsigned* gen, unsigned ep) {
    __syncthreads();
    const int tid = threadIdx.x;
    if (blockIdx.x == 0) {
        if (tid == 0) {
            __threadfence();  // release: flush our XCD L2 to coherence point
            __hip_atomic_store(arr, ep, __ATOMIC_RELEASE, __HIP_MEMORY_SCOPE_AGENT);
        }
        // 256 threads poll 256 slots in parallel (one latency per round)
        while (__hip_atomic_load(arr + tid * 32, __ATOMIC_RELAXED, __HIP_MEMORY_SCOPE_AGENT) < ep)
            __builtin_amdgcn_s_sleep(2);
        __syncthreads();
        if (tid == 0) {
            __hip_atomic_store(gen, ep, __ATOMIC_RELEASE, __HIP_MEMORY_SCOPE_AGENT);
            __threadfence();  // acquire: invalidate so we read others' fresh data
        }
    } else {
        if (tid == 0) {
            __threadfence();
            __hip_atomic_store(arr + blockIdx.x * 32, ep, __ATOMIC_RELEASE, __HIP_MEMORY_SCOPE_AGENT);
            while (__hip_atomic_load(gen, __ATOMIC_RELAXED, __HIP_MEMORY_SCOPE_AGENT) < ep)
                __builtin_amdgcn_s_sleep(8);
            __threadfence();
        }
    }
    __syncthreads();
}

// ---- one 16x64 output tile of D[M,512] = A[M,512] @ Bt[512,512]^T (bf16 in, bf16 out) ----
__device__ __forceinline__ void gemm16x64(const us* __restrict__ A, const us* __restrict__ Bt,
                                          us* __restrict__ D, int m0, int n0, int lane) {
    int l15 = lane & 15, quad = lane >> 4;
    f32x4 acc[4] = {};
    const us* Ar = A + (size_t)(m0 + l15) * HH + quad * 8;
    const us* Br = Bt + (size_t)(n0 + l15) * HH + quad * 8;
#pragma unroll 4
    for (int kk = 0; kk < 16; ++kk) {
        bf16x8 a = ldb8(Ar + kk * 32);
#pragma unroll
        for (int tt = 0; tt < 4; ++tt) {
            bf16x8 b = ldb8(Br + (size_t)tt * 16 * HH + kk * 32);
            acc[tt] = __builtin_amdgcn_mfma_f32_16x16x32_bf16(a, b, acc[tt], 0, 0, 0);
        }
    }
#pragma unroll
    for (int tt = 0; tt < 4; ++tt)
#pragma unroll
        for (int r = 0; r < 4; ++r)
            D[(size_t)(m0 + quad * 4 + r) * HH + n0 + tt * 16 + l15] = f2bf(acc[tt][r]);
}

// ================= the whole model: one persistent kernel =================
__global__ __launch_bounds__(256, 1) void k_all(
    const int* __restrict__ xs, const int* __restrict__ argsort,
    const float* __restrict__ enc_Wi, const float* __restrict__ enc_Wh, const float* __restrict__ enc_b,
    const float* __restrict__ dec_Wi, const float* __restrict__ dec_Wh, const float* __restrict__ dec_b,
    const float* __restrict__ w1, const float* __restrict__ w2, const float* __restrict__ vt,
    float* __restrict__ out, char* __restrict__ ws) {
    unsigned* gen = (unsigned*)ws;              // 4B
    unsigned* arr = (unsigned*)(ws + 128);      // 256 slots x 128B = 32768 -> 32896
    float* din = (float*)(ws + 32896);          // 2*256*4 = 2048 -> 34944 (zeroed)
    us* hdec = (us*)(ws + 34944);               // 2*256*512*2 -> 559232
    us* q = (us*)(ws + 559232);                 // 256*512*2   -> 821376
    us* ctx = (us*)(ws + 821376);               // 256*512*2   -> 1083520
    us* wiR = (us*)(ws + 1083520);              // 2048*512*2  -> 3180672
    us* whE = (us*)(ws + 3180672);              // 2048*512*2  -> 5277824
    us* whD = (us*)(ws + 5277824);              // 2048*512*2  -> 7374976
    us* w1B = (us*)(ws + 7374976);              // 512*512*2   -> 7899264
    us* w2B = (us*)(ws + 7899264);              // 512*512*2   -> 8423552
    us* enc_out = (us*)(ws + 8423552);          // 256*128*512*2 -> 41977984
    us* enc_w1 = (us*)(ws + 41977984);          // 256*128*512*2 -> 75532416

    __shared__ float scs[LL];
    __shared__ float aj[LL];
    __shared__ float redm[2];
    __shared__ float reds[2];

    const int tid = threadIdx.x, blk = blockIdx.x;
    const int w = tid >> 6, lane = tid & 63;
    const int l15 = lane & 15, quad = lane >> 4;
    const int gw = blk * 4 + w;       // 0..1023
    const int t2 = blk * 2 + w;       // wave-task id for w<2: 0..511
    const bool encw = (w < 2);
    unsigned ep = 0;

    // ---- phase 0: weight conversion f32 -> bf16 ws copies ----
    for (int i = blk * 256 + tid; i < H4 * HH; i += 65536) {
        whE[i] = f2bf(enc_Wh[i]);
        whD[i] = f2bf(dec_Wh[i]);
        int r = i >> 9, c = i & 511;
        wiR[i] = f2bf(dec_Wi[(size_t)r * 513 + c]);
    }
    for (int i = blk * 256 + tid; i < HH * HH; i += 65536) {
        w1B[i] = f2bf(w1[i]);
        w2B[i] = f2bf(w2[i]);
    }
    gridbar(arr, gen, ++ep);

    // ---- per-task constants (hoisted out of the time loops) ----
    int b0 = 0, c0 = 0, col = 0;
    float biE[4], wiE[4], biD[4], wlD[4];
    if (encw) {
        b0 = (t2 & 15) * 16;
        c0 = (t2 >> 4) * 16;
        col = c0 + l15;
#pragma unroll
        for (int g = 0; g < 4; ++g) {
            int rg = g * HH + col;
            biE[g] = enc_b[rg];
            wiE[g] = enc_Wi[rg];
            biD[g] = dec_b[rg];
            wlD[g] = dec_Wi[(size_t)rg * 513 + 512];
        }
    }
    float creg[4] = {0.f, 0.f, 0.f, 0.f};  // LSTM c, lives in regs encoder->decoder

    // ---- phase 1: encoder, 128 steps, 1 barrier each ----
    for (int t = 0; t < LL; ++t) {
        if (encw) {
            f32x4 acc[4] = {};
            if (t > 0) {
                const us* Arow = enc_out + ((size_t)(b0 + l15) * LL + (t - 1)) * HH + quad * 8;
                const us* Brow = whE + (size_t)(c0 + l15) * HH + quad * 8;
#pragma unroll 4
                for (int kk = 0; kk < 16; ++kk) {
                    bf16x8 a = ldb8(Arow + kk * 32);
#pragma unroll
                    for (int g = 0; g < 4; ++g) {
                        bf16x8 b = ldb8(Brow + (size_t)g * HH * HH + kk * 32);
                        acc[g] = __builtin_amdgcn_mfma_f32_16x16x32_bf16(a, b, acc[g], 0, 0, 0);
                    }
                }
            }
#pragma unroll
            for (int r = 0; r < 4; ++r) {
                int b = b0 + quad * 4 + r;
                float xv = (float)xs[b * LL + t];
                float zi = acc[0][r] + biE[0] + xv * wiE[0];
                float zf = acc[1][r] + biE[1] + xv * wiE[1];
                float zg = acc[2][r] + biE[2] + xv * wiE[2];
                float zo = acc[3][r] + biE[3] + xv * wiE[3];
                float c_ = sigm(zf) * creg[r] + sigm(zi) * tanh_(zg);
                creg[r] = c_;
                us hb = f2bf(sigm(zo) * tanh_(c_));
                enc_out[((size_t)b * LL + t) * HH + col] = hb;
                if (t == LL - 1) hdec[(size_t)b * HH + col] = hb;
            }
        }
        gridbar(arr, gen, ++ep);
    }

    // ---- phase 2: enc_w1 = enc_out @ w1^T (16384 wave-tasks over 1024 waves) ----
    for (int task = gw; task < 16384; task += 1024) {
        int m0 = (task >> 3) * 16, n0 = (task & 7) * 64;
        gemm16x64(enc_out, w1B, enc_w1, m0, n0, lane);
    }
    gridbar(arr, gen, ++ep);

    // ---- phase 3: decoder, 128 steps, 3 barriers each ----
    const int k0 = lane * 8;
    float vtk[8];
#pragma unroll
    for (int j = 0; j < 8; ++j) vtk[j] = vt[k0 + j];

    for (int t = 0; t < LL; ++t) {
        us* hcur = hdec + (size_t)(t & 1) * BB * HH;
        us* hnxt = hdec + (size_t)((t + 1) & 1) * BB * HH;
        float* dcur = din + (t & 1) * BB;
        float* dnxt = din + ((t + 1) & 1) * BB;

        // q = hcur @ w2^T : 128 wave-tasks on even blocks' wave 0
        if (w == 0 && (blk & 1) == 0) {
            int qt = blk >> 1;
            gemm16x64(hcur, w2B, q, (qt >> 3) * 16, (qt & 7) * 64, lane);
        }
        gridbar(arr, gen, ++ep);

        // attention: block handles batch b = blk (256 threads)
        {
            bf16x8 qv = ldb8(q + (size_t)blk * HH + k0);
            float qk[8];
#pragma unroll
            for (int j = 0; j < 8; ++j) qk[j] = (float)qv[j];
            const us* wbase = enc_w1 + (size_t)blk * LL * HH + k0;
#pragma unroll 4
            for (int i = 0; i < 32; ++i) {
                int l = i * 4 + w;
                bf16x8 e8 = ldb8(wbase + (size_t)l * HH);
                float s = 0.f;
#pragma unroll
                for (int j = 0; j < 8; ++j) s += tanh_((float)e8[j] + qk[j]) * vtk[j];
#pragma unroll
                for (int off = 1; off < 64; off <<= 1) s += __shfl_xor(s, off);
                if (lane == 0) scs[l] = s;
            }
            __syncthreads();
            bool act = tid < 128;
            float sc = act ? scs[tid] : -1e30f;
            float m = sc;
#pragma unroll
            for (int off = 1; off < 64; off <<= 1) m = fmaxf(m, __shfl_xor(m, off));
            if (act && lane == 0) redm[w] = m;
            __syncthreads();
            float M = fmaxf(redm[0], redm[1]);
            float e = act ? __expf(sc - M) : 0.f;
            float ss = e;
#pragma unroll
            for (int off = 1; off < 64; off <<= 1) ss += __shfl_xor(ss, off);
            if (act && lane == 0) reds[w] = ss;
            __syncthreads();
            float S = reds[0] + reds[1];
            if (act) {
                out[((size_t)blk * LL + t) * LL + tid] = sc - M - __logf(S);
                aj[tid] = e / S;
            }
            __syncthreads();
            const us* ep2 = enc_out + (size_t)blk * LL * HH + tid;
            float cx0 = 0.f, cx1 = 0.f;
#pragma unroll 8
            for (int l2 = 0; l2 < LL; ++l2) {
                cx0 += aj[l2] * bf2f(ep2[(size_t)l2 * HH]);
                cx1 += aj[l2] * bf2f(ep2[(size_t)l2 * HH + 256]);
            }
            ctx[(size_t)blk * HH + tid] = f2bf(cx0);
            ctx[(size_t)blk * HH + tid + 256] = f2bf(cx1);
            if (tid == 0) {
                int idx = argsort[blk * LL + t];
                dnxt[blk] = (float)xs[blk * LL + idx];
            }
        }
        gridbar(arr, gen, ++ep);

        // decoder LSTM: z = [ctx,din]@Wi^T + h@Wh^T + b (same task map as encoder)
        if (encw) {
            f32x4 acc[4] = {};
            const us* A1 = ctx + (size_t)(b0 + l15) * HH + quad * 8;
            const us* B1 = wiR + (size_t)(c0 + l15) * HH + quad * 8;
#pragma unroll 4
            for (int kk = 0; kk < 16; ++kk) {
                bf16x8 a = ldb8(A1 + kk * 32);
#pragma unroll
                for (int g = 0; g < 4; ++g) {
                    bf16x8 b = ldb8(B1 + (size_t)g * HH * HH + kk * 32);
                    acc[g] = __builtin_amdgcn_mfma_f32_16x16x32_bf16(a, b, acc[g], 0, 0, 0);
                }
            }
            const us* A2 = hcur + (size_t)(b0 + l15) * HH + quad * 8;
            const us* B2 = whD + (size_t)(c0 + l15) * HH + quad * 8;
#pragma unroll 4
            for (int kk = 0; kk < 16; ++kk) {
                bf16x8 a = ldb8(A2 + kk * 32);
#pragma unroll
                for (int g = 0; g < 4; ++g) {
                    bf16x8 b = ldb8(B2 + (size_t)g * HH * HH + kk * 32);
                    acc[g] = __builtin_amdgcn_mfma_f32_16x16x32_bf16(a, b, acc[g], 0, 0, 0);
                }
            }
#pragma unroll
            for (int r = 0; r < 4; ++r) {
                int b = b0 + quad * 4 + r;
                float dv = dcur[b];
                float zi = acc[0][r] + biD[0] + dv * wlD[0];
                float zf = acc[1][r] + biD[1] + dv * wlD[1];
                float zg = acc[2][r] + biD[2] + dv * wlD[2];
                float zo = acc[3][r] + biD[3] + dv * wlD[3];
                float c_ = sigm(zf) * creg[r] + sigm(zi) * tanh_(zg);
                creg[r] = c_;
                hnxt[(size_t)b * HH + col] = f2bf(sigm(zo) * tanh_(c_));
            }
        }
        gridbar(arr, gen, ++ep);
    }
}

extern "C" void kernel_launch(void* const* d_in, const int* in_sizes, int n_in,
                              void* d_out, int out_size, void* d_ws, size_t ws_size,
                              hipStream_t stream) {
    const int* xs = (const int*)d_in[0];
    const int* argsort = (const int*)d_in[2];
    const float* enc_Wi = (const float*)d_in[3];
    const float* enc_Wh = (const float*)d_in[4];
    const float* enc_b = (const float*)d_in[5];
    const float* dec_Wi = (const float*)d_in[6];
    const float* dec_Wh = (const float*)d_in[7];
    const float* dec_b = (const float*)d_in[8];
    const float* w1 = (const float*)d_in[9];
    const float* w2 = (const float*)d_in[10];
    const float* vt = (const float*)d_in[11];
    float* out = (float*)d_out;
    char* ws = (char*)d_ws;

    // zero gen + arrive slots + din double-buffer
    hipMemsetAsync(ws, 0, 34944, stream);
    k_all<<<256, 256, 0, stream>>>(xs, argsort, enc_Wi, enc_Wh, enc_b,
                                   dec_Wi, dec_Wh, dec_b, w1, w2, vt, out, ws);
    (void)in_sizes; (void)n_in; (void)out_size; (void)ws_size;
}

// Round 6
// 11500.712 us; speedup vs baseline: 1.9046x; 1.2404x over previous
//
#include <hip/hip_runtime.h>

#define BB 256
#define LL 128
#define HH 512
#define H4 2048

typedef unsigned short us;
typedef __attribute__((ext_vector_type(8))) __bf16 bf16x8;
typedef __attribute__((ext_vector_type(4))) float f32x4;

__device__ __forceinline__ float bf2f(us s) {
    unsigned u = ((unsigned)s) << 16;
    return __builtin_bit_cast(float, u);
}
__device__ __forceinline__ us f2bf(float f) {
    unsigned u = __builtin_bit_cast(unsigned, f);
    return (us)((u + 0x7fffu + ((u >> 16) & 1u)) >> 16);
}
__device__ __forceinline__ float sigm(float x) { return 1.f / (1.f + __expf(-x)); }
__device__ __forceinline__ float tanh_(float x) { return 1.f - 2.f / (1.f + __expf(2.f * x)); }
__device__ __forceinline__ bf16x8 ldb8(const us* p) { return *(const bf16x8*)(const void*)p; }

// device-scope (coherence-point) 8B load, bypasses L1/L2 — for addresses that get rewritten
__device__ __forceinline__ unsigned long long ldu64(const void* p) {
    return __hip_atomic_load((const unsigned long long*)p, __ATOMIC_RELAXED, __HIP_MEMORY_SCOPE_AGENT);
}
__device__ __forceinline__ bf16x8 ld8u(const us* p) {
    union { unsigned long long u[2]; bf16x8 v; } x;
    x.u[0] = ldu64(p);
    x.u[1] = ldu64(p + 4);
    return x.v;
}
// lane-paired device-scope store: lanes (2i,2i+1) hold bf16 for adjacent addresses;
// even lane stores one u32 at the coherence point (no dirty L2 line -> no wbl2 needed)
__device__ __forceinline__ void stp(us* my_addr, us val, int lane) {
    unsigned mine = val;
    unsigned other = __shfl_xor(mine, 1);
    if (!(lane & 1)) {
        unsigned pk = mine | (other << 16);
        __hip_atomic_store((unsigned*)(void*)my_addr, pk, __ATOMIC_RELAXED, __HIP_MEMORY_SCOPE_AGENT);
    }
}

// ---- fence-free grid barrier: per-block arrive slots + block-0 parallel gather ----
// All cross-block data is written with device-scope stores (already at L3), so no
// threadfence/wbl2/inv is needed. __syncthreads drains each wave's vmcnt first.
__device__ __forceinline__ void gridbar(unsigned* arr, unsigned* gen, unsigned ep) {
    __builtin_amdgcn_s_waitcnt(0);
    __syncthreads();
    const int tid = threadIdx.x;
    if (blockIdx.x == 0) {
        if (tid == 0) __hip_atomic_store(arr, ep, __ATOMIC_RELAXED, __HIP_MEMORY_SCOPE_AGENT);
        while (__hip_atomic_load(arr + (size_t)tid * 32, __ATOMIC_RELAXED, __HIP_MEMORY_SCOPE_AGENT) < ep)
            __builtin_amdgcn_s_sleep(2);
        __syncthreads();
        if (tid == 0) __hip_atomic_store(gen, ep, __ATOMIC_RELAXED, __HIP_MEMORY_SCOPE_AGENT);
    } else if (tid == 0) {
        __hip_atomic_store(arr + (size_t)blockIdx.x * 32, ep, __ATOMIC_RELAXED, __HIP_MEMORY_SCOPE_AGENT);
        while (__hip_atomic_load(gen, __ATOMIC_RELAXED, __HIP_MEMORY_SCOPE_AGENT) < ep)
            __builtin_amdgcn_s_sleep(4);
    }
    __syncthreads();
}

// ---- one 16x64 tile of D[M,512] = A[M,512] @ Bt[512,512]^T; cached reads, paired stores ----
__device__ __forceinline__ void gemm16x64(const us* __restrict__ A, const us* __restrict__ Bt,
                                          us* __restrict__ D, int m0, int n0, int lane) {
    int l15 = lane & 15, quad = lane >> 4;
    f32x4 acc[4] = {};
    const us* Ar = A + (size_t)(m0 + l15) * HH + quad * 8;
    const us* Br = Bt + (size_t)(n0 + l15) * HH + quad * 8;
#pragma unroll 4
    for (int kk = 0; kk < 16; ++kk) {
        bf16x8 a = ldb8(Ar + kk * 32);
#pragma unroll
        for (int tt = 0; tt < 4; ++tt) {
            bf16x8 b = ldb8(Br + (size_t)tt * 16 * HH + kk * 32);
            acc[tt] = __builtin_amdgcn_mfma_f32_16x16x32_bf16(a, b, acc[tt], 0, 0, 0);
        }
    }
#pragma unroll
    for (int tt = 0; tt < 4; ++tt)
#pragma unroll
        for (int r = 0; r < 4; ++r)
            stp(D + (size_t)(m0 + quad * 4 + r) * HH + n0 + tt * 16 + l15, f2bf(acc[tt][r]), lane);
}

// ================= the whole model: one persistent kernel =================
__global__ __launch_bounds__(256, 1) void k_all(
    const int* __restrict__ xs, const int* __restrict__ argsort,
    const float* __restrict__ enc_Wi, const float* __restrict__ enc_Wh, const float* __restrict__ enc_b,
    const float* __restrict__ dec_Wi, const float* __restrict__ dec_Wh, const float* __restrict__ dec_b,
    const float* __restrict__ w1, const float* __restrict__ w2, const float* __restrict__ vt,
    float* __restrict__ out, char* __restrict__ ws) {
    unsigned* gen = (unsigned*)ws;              // 4B
    unsigned* arr = (unsigned*)(ws + 128);      // 256 slots x 128B -> 32896
    float* din = (float*)(ws + 32896);          // 2*256*4 -> 34944 (zeroed)
    us* hdec = (us*)(ws + 34944);               // 2*256*512*2 -> 559232
    us* ctx = (us*)(ws + 821376);               // 256*512*2   -> 1083520
    us* wiR = (us*)(ws + 1083520);              // 2048*512*2  -> 3180672
    us* whE = (us*)(ws + 3180672);              // 2048*512*2  -> 5277824
    us* whD = (us*)(ws + 5277824);              // 2048*512*2  -> 7374976
    us* w1B = (us*)(ws + 7374976);              // 512*512*2   -> 7899264
    us* w2B = (us*)(ws + 7899264);              // 512*512*2   -> 8423552
    us* enc_out = (us*)(ws + 8423552);          // 256*128*512*2 -> 41977984
    us* enc_w1 = (us*)(ws + 41977984);          // 256*128*512*2 -> 75532416

    __shared__ float hs[HH];
    __shared__ float qs[HH];
    __shared__ float scs[LL];
    __shared__ float aj[LL];
    __shared__ float redm[2];
    __shared__ float reds[2];

    const int tid = threadIdx.x, blk = blockIdx.x;
    const int w = tid >> 6, lane = tid & 63;
    const int l15 = lane & 15, quad = lane >> 4;
    const int gw = blk * 4 + w;       // 0..1023
    const int t2 = blk * 2 + w;       // wave-task id for w<2: 0..511
    const bool encw = (w < 2);
    unsigned ep = 0;

    // ---- phase 0: weight conversion f32 -> bf16 (device-scope paired stores) ----
    for (int i = blk * 256 + tid; i < H4 * HH; i += 65536) {
        stp(&whE[i], f2bf(enc_Wh[i]), lane);
        stp(&whD[i], f2bf(dec_Wh[i]), lane);
        int r = i >> 9, c = i & 511;
        stp(&wiR[i], f2bf(dec_Wi[(size_t)r * 513 + c]), lane);
    }
    for (int i = blk * 256 + tid; i < HH * HH; i += 65536) {
        stp(&w1B[i], f2bf(w1[i]), lane);
        stp(&w2B[i], f2bf(w2[i]), lane);
    }
    gridbar(arr, gen, ++ep);

    // ---- per-task constants ----
    int b0 = 0, c0 = 0, col = 0;
    float biE[4], wiE[4], biD[4], wlD[4];
    if (encw) {
        b0 = (t2 & 15) * 16;
        c0 = (t2 >> 4) * 16;
        col = c0 + l15;
#pragma unroll
        for (int g = 0; g < 4; ++g) {
            int rg = g * HH + col;
            biE[g] = enc_b[rg];
            wiE[g] = enc_Wi[rg];
            biD[g] = dec_b[rg];
            wlD[g] = dec_Wi[(size_t)rg * 513 + 512];
        }
    }
    float creg[4] = {0.f, 0.f, 0.f, 0.f};  // LSTM c: registers, encoder -> decoder

    // ---- phase 1: encoder, 128 steps, 1 barrier each ----
    for (int t = 0; t < LL; ++t) {
        if (encw) {
            f32x4 acc[4] = {};
            if (t > 0) {
                // A addresses (.,t-1,.) are written exactly once -> cached reads are safe
                const us* Arow = enc_out + ((size_t)(b0 + l15) * LL + (t - 1)) * HH + quad * 8;
                const us* Brow = whE + (size_t)(c0 + l15) * HH + quad * 8;
#pragma unroll 4
                for (int kk = 0; kk < 16; ++kk) {
                    bf16x8 a = ldb8(Arow + kk * 32);
#pragma unroll
                    for (int g = 0; g < 4; ++g) {
                        bf16x8 b = ldb8(Brow + (size_t)g * HH * HH + kk * 32);
                        acc[g] = __builtin_amdgcn_mfma_f32_16x16x32_bf16(a, b, acc[g], 0, 0, 0);
                    }
                }
            }
#pragma unroll
            for (int r = 0; r < 4; ++r) {
                int b = b0 + quad * 4 + r;
                float xv = (float)xs[b * LL + t];
                float zi = acc[0][r] + biE[0] + xv * wiE[0];
                float zf = acc[1][r] + biE[1] + xv * wiE[1];
                float zg = acc[2][r] + biE[2] + xv * wiE[2];
                float zo = acc[3][r] + biE[3] + xv * wiE[3];
                float c_ = sigm(zf) * creg[r] + sigm(zi) * tanh_(zg);
                creg[r] = c_;
                us hb = f2bf(sigm(zo) * tanh_(c_));
                stp(&enc_out[((size_t)b * LL + t) * HH + col], hb, lane);
                if (t == LL - 1) stp(&hdec[(size_t)b * HH + col], hb, lane);
            }
        }
        gridbar(arr, gen, ++ep);
    }

    // ---- phase 2: enc_w1 = enc_out @ w1^T (16384 wave-tasks over 1024 waves) ----
    for (int task = gw; task < 16384; task += 1024) {
        int m0 = (task >> 3) * 16, n0 = (task & 7) * 64;
        gemm16x64(enc_out, w1B, enc_w1, m0, n0, lane);
    }
    gridbar(arr, gen, ++ep);

    // ---- phase 3: decoder, 128 steps, 2 barriers each (q fused into attention) ----
    const int k0 = lane * 8;
    float vtk[8];
#pragma unroll
    for (int j = 0; j < 8; ++j) vtk[j] = vt[k0 + j];

    for (int t = 0; t < LL; ++t) {
        us* hcur = hdec + (size_t)(t & 1) * BB * HH;
        us* hnxt = hdec + (size_t)((t + 1) & 1) * BB * HH;
        float* dcur = din + (t & 1) * BB;
        float* dnxt = din + ((t + 1) & 1) * BB;

        // ---- attention for batch b = blk (256 threads), q computed in-block ----
        if (tid < 128) {  // load h[b] (rewritten addresses -> device-scope load)
            unsigned long long v = ldu64(hcur + (size_t)blk * HH + tid * 4);
#pragma unroll
            for (int j = 0; j < 4; ++j) hs[tid * 4 + j] = bf2f((us)(v >> (16 * j)));
        }
        __syncthreads();
        {   // q[k] = sum_j h[j] * w2[k][j]; thread: k = tid, tid+256 (w2B cached, L2-resident)
            float a0 = 0.f, a1 = 0.f;
            const us* r0 = w2B + (size_t)tid * HH;
            const us* r1 = w2B + (size_t)(tid + 256) * HH;
            for (int j = 0; j < HH; j += 8) {
                bf16x8 x0 = ldb8(r0 + j);
                bf16x8 x1 = ldb8(r1 + j);
                const float* hp = hs + j;
#pragma unroll
                for (int jj = 0; jj < 8; ++jj) {
                    float hv = hp[jj];
                    a0 += hv * (float)x0[jj];
                    a1 += hv * (float)x1[jj];
                }
            }
            qs[tid] = a0;
            qs[tid + 256] = a1;
        }
        __syncthreads();
        {
            float qk[8];
#pragma unroll
            for (int j = 0; j < 8; ++j) qk[j] = qs[k0 + j];
            const us* wbase = enc_w1 + (size_t)blk * LL * HH + k0;  // once-written -> cached
#pragma unroll 4
            for (int i = 0; i < 32; ++i) {
                int l = i * 4 + w;
                bf16x8 e8 = ldb8(wbase + (size_t)l * HH);
                float s = 0.f;
#pragma unroll
                for (int j = 0; j < 8; ++j) s += tanh_((float)e8[j] + qk[j]) * vtk[j];
#pragma unroll
                for (int off = 1; off < 64; off <<= 1) s += __shfl_xor(s, off);
                if (lane == 0) scs[l] = s;
            }
            __syncthreads();
            bool act = tid < 128;
            float sc = act ? scs[tid] : -1e30f;
            float m = sc;
#pragma unroll
            for (int off = 1; off < 64; off <<= 1) m = fmaxf(m, __shfl_xor(m, off));
            if (act && lane == 0) redm[w] = m;
            __syncthreads();
            float M = fmaxf(redm[0], redm[1]);
            float e = act ? __expf(sc - M) : 0.f;
            float ss = e;
#pragma unroll
            for (int off = 1; off < 64; off <<= 1) ss += __shfl_xor(ss, off);
            if (act && lane == 0) reds[w] = ss;
            __syncthreads();
            float S = reds[0] + reds[1];
            if (act) {
                out[((size_t)blk * LL + t) * LL + tid] = sc - M - __logf(S);
                aj[tid] = e / S;
            }
            __syncthreads();
            const us* ep2 = enc_out + (size_t)blk * LL * HH + tid;  // once-written -> cached
            float cx0 = 0.f, cx1 = 0.f;
#pragma unroll 8
            for (int l2 = 0; l2 < LL; ++l2) {
                cx0 += aj[l2] * bf2f(ep2[(size_t)l2 * HH]);
                cx1 += aj[l2] * bf2f(ep2[(size_t)l2 * HH + 256]);
            }
            stp(&ctx[(size_t)blk * HH + tid], f2bf(cx0), lane);
            stp(&ctx[(size_t)blk * HH + tid + 256], f2bf(cx1), lane);
            if (tid == 0) {
                int idx = argsort[blk * LL + t];
                __hip_atomic_store((unsigned*)(void*)(dnxt + blk),
                                   __builtin_bit_cast(unsigned, (float)xs[blk * LL + idx]),
                                   __ATOMIC_RELAXED, __HIP_MEMORY_SCOPE_AGENT);
            }
        }
        gridbar(arr, gen, ++ep);

        // ---- decoder LSTM (same task map as encoder); ctx/h device-scope reads ----
        if (encw) {
            f32x4 acc[4] = {};
            const us* A1 = ctx + (size_t)(b0 + l15) * HH + quad * 8;
            const us* B1 = wiR + (size_t)(c0 + l15) * HH + quad * 8;
#pragma unroll 4
            for (int kk = 0; kk < 16; ++kk) {
                bf16x8 a = ld8u(A1 + kk * 32);
#pragma unroll
                for (int g = 0; g < 4; ++g) {
                    bf16x8 b = ldb8(B1 + (size_t)g * HH * HH + kk * 32);
                    acc[g] = __builtin_amdgcn_mfma_f32_16x16x32_bf16(a, b, acc[g], 0, 0, 0);
                }
            }
            const us* A2 = hcur + (size_t)(b0 + l15) * HH + quad * 8;
            const us* B2 = whD + (size_t)(c0 + l15) * HH + quad * 8;
#pragma unroll 4
            for (int kk = 0; kk < 16; ++kk) {
                bf16x8 a = ld8u(A2 + kk * 32);
#pragma unroll
                for (int g = 0; g < 4; ++g) {
                    bf16x8 b = ldb8(B2 + (size_t)g * HH * HH + kk * 32);
                    acc[g] = __builtin_amdgcn_mfma_f32_16x16x32_bf16(a, b, acc[g], 0, 0, 0);
                }
            }
#pragma unroll
            for (int r = 0; r < 4; ++r) {
                int b = b0 + quad * 4 + r;
                float dv = __builtin_bit_cast(float,
                    __hip_atomic_load((const unsigned*)(const void*)(dcur + b),
                                      __ATOMIC_RELAXED, __HIP_MEMORY_SCOPE_AGENT));
                float zi = acc[0][r] + biD[0] + dv * wlD[0];
                float zf = acc[1][r] + biD[1] + dv * wlD[1];
                float zg = acc[2][r] + biD[2] + dv * wlD[2];
                float zo = acc[3][r] + biD[3] + dv * wlD[3];
                float c_ = sigm(zf) * creg[r] + sigm(zi) * tanh_(zg);
                creg[r] = c_;
                stp(&hnxt[(size_t)b * HH + col], f2bf(sigm(zo) * tanh_(c_)), lane);
            }
        }
        gridbar(arr, gen, ++ep);
    }
}

extern "C" void kernel_launch(void* const* d_in, const int* in_sizes, int n_in,
                              void* d_out, int out_size, void* d_ws, size_t ws_size,
                              hipStream_t stream) {
    const int* xs = (const int*)d_in[0];
    const int* argsort = (const int*)d_in[2];
    const float* enc_Wi = (const float*)d_in[3];
    const float* enc_Wh = (const float*)d_in[4];
    const float* enc_b = (const float*)d_in[5];
    const float* dec_Wi = (const float*)d_in[6];
    const float* dec_Wh = (const float*)d_in[7];
    const float* dec_b = (const float*)d_in[8];
    const float* w1 = (const float*)d_in[9];
    const float* w2 = (const float*)d_in[10];
    const float* vt = (const float*)d_in[11];
    float* out = (float*)d_out;
    char* ws = (char*)d_ws;

    // zero gen + arrive slots + din double-buffer
    hipMemsetAsync(ws, 0, 34944, stream);
    k_all<<<256, 256, 0, stream>>>(xs, argsort, enc_Wi, enc_Wh, enc_b,
                                   dec_Wi, dec_Wh, dec_b, w1, w2, vt, out, ws);
    (void)in_sizes; (void)n_in; (void)out_size; (void)ws_size;
}